// Round 15
// baseline (405.725 us; speedup 1.0000x reference)
//
#include <hip/hip_runtime.h>

#define NR 8192
#define FIN 2048
#define FOUT 256
#define ALPHA 0.2f
#define NTMAX 136
#define KS 4
#define KLEN 512
#define NSTEPS 16
#define JC 4
#define NJ 2048

typedef float f32x4 __attribute__((ext_vector_type(4)));
typedef float f32x16 __attribute__((ext_vector_type(16)));
typedef int i32x4 __attribute__((ext_vector_type(4)));
typedef unsigned int u32x4 __attribute__((ext_vector_type(4)));
typedef unsigned short u16x4 __attribute__((ext_vector_type(4)));
typedef unsigned short u16x8 __attribute__((ext_vector_type(8)));
typedef __bf16 bf16x8 __attribute__((ext_vector_type(8)));
typedef _Float16 f16x8 __attribute__((ext_vector_type(8)));

__device__ __forceinline__ unsigned short f2bf(float f){
  unsigned u = __float_as_uint(f);
  return (unsigned short)((u + 0x7fffu + ((u >> 16) & 1u)) >> 16);
}
__device__ __forceinline__ float bf2f(unsigned short b){
  return __uint_as_float(((unsigned)b) << 16);
}
__device__ __forceinline__ void gload16(const void* gptr, void* lptr){
  __builtin_amdgcn_global_load_lds(
      (const __attribute__((address_space(1))) unsigned int*)gptr,
      (__attribute__((address_space(3))) unsigned int*)lptr, 16, 0, 0);
}

// ---------------- K1: fused wth (blocks 0..1023) + bucket (block 1024) --------
// Also zeroes the flash last-block counters (fcnt[128]) every call.
__global__ __launch_bounds__(256) void k_pre(const float* __restrict__ W,
    _Float16* __restrict__ WhT, const int* __restrict__ cam,
    int* __restrict__ prows, int* __restrict__ tileCam,
    int* __restrict__ fcnt){
  __shared__ __align__(16) char smem[9216];
  int blk = blockIdx.x, t = threadIdx.x;
  if (blk < 1024){
    _Float16 (*tl)[72] = (_Float16(*)[72])smem;
    int k0 = (blk & 31) << 6;
    int n0 = ((blk >> 5) & 3) << 6;
    int c = blk >> 7;
    {
      int kk = t >> 2, nq = (t & 3)*16;
      const float* src = W + ((size_t)c*FIN + k0 + kk)*FOUT + n0 + nq;
      #pragma unroll
      for (int q = 0; q < 4; q++){
        f32x4 v = *(const f32x4*)(src + q*4);
        #pragma unroll
        for (int e = 0; e < 4; e++) tl[nq + q*4 + e][kk] = (_Float16)v[e];
      }
    }
    __syncthreads();
    {
      int nn = t >> 2, kq = (t & 3)*16;
      union { u32x4 v[2]; _Float16 s[16]; } buf;
      #pragma unroll
      for (int e = 0; e < 16; e++) buf.s[e] = tl[nn][kq + e];
      u32x4* dst = (u32x4*)(WhT + ((size_t)c*FOUT + n0 + nn)*FIN + k0 + kq);
      dst[0] = buf.v[0]; dst[1] = buf.v[1];
    }
  } else {
    if (t < 128) fcnt[t] = 0;
    int (*cnt)[8] = (int(*)[8])smem;          // [256][8]
    int* scnt = (int*)(smem + 8192);          // [8]
    int* tst  = (int*)(smem + 8224);          // [9]
    int loc[8];
    #pragma unroll
    for (int c = 0; c < 8; c++) loc[c] = 0;
    for (int k = 0; k < 32; k++) loc[cam[t*32 + k] & 7]++;
    #pragma unroll
    for (int c = 0; c < 8; c++) cnt[t][c] = loc[c];
    __syncthreads();
    if (t < 8){
      int s = 0;
      for (int i = 0; i < 256; i++){ int v = cnt[i][t]; cnt[i][t] = s; s += v; }
      scnt[t] = s;
    }
    __syncthreads();
    if (t == 0){
      int ts = 0;
      for (int c = 0; c < 8; c++){ tst[c] = ts; ts += (scnt[c] + 63) >> 6; }
      tst[8] = ts;
    }
    __syncthreads();
    for (int s = t; s < NTMAX*64; s += 256) prows[s] = -1;
    if (t < NTMAX){
      int tc = -1, te = tst[8];
      if (t < te){
        #pragma unroll
        for (int c = 0; c < 8; c++)
          if (t >= tst[c] && t < tst[c+1]) tc = c;
      }
      tileCam[t] = tc;
    }
    __syncthreads();
    int off[8];
    #pragma unroll
    for (int c = 0; c < 8; c++) off[c] = cnt[t][c];
    for (int k = 0; k < 32; k++){
      int n = t*32 + k; int c = cam[n] & 7;
      int slot = off[c]++;
      prows[(tst[c] + (slot >> 6))*64 + (slot & 63)] = n;
    }
  }
}

// ---------------- K2: MFMA gather GEMM  partial[ks] = x[rows] @ W[c] ----------
__global__ __launch_bounds__(256, 3) void k_gmm(const float* __restrict__ x,
    const _Float16* __restrict__ WhT, const int* __restrict__ tileCam,
    const int* __restrict__ prows, float* __restrict__ partial){
  __shared__ __align__(16) char smem[41728];
  int item = blockIdx.x;
  int tile = item >> 2, ks = item & 3;
  int camc = tileCam[tile];
  if (camc < 0) return;
  _Float16* ab = (_Float16*)smem;            // [2][10240]
  int* rows  = (int*)(smem + 40960);         // [64]
  int* growL = (int*)(smem + 41216);         // [64]
  int t = threadIdx.x;
  if (t < 64){
    int r = prows[tile*64 + t];
    rows[t] = r; growL[t] = (r < 0) ? 0 : r;
  }
  __syncthreads();
  int lane = t & 63, w = t >> 6;
  int k0 = ks * KLEN;
  int wr = w >> 1, wc = w & 1;
  int rA = ((t >> 6) & 1)*32 + (t & 31);
  int koffA = (t >> 7)*16 + ((t >> 5) & 1)*8;
  const float* srcA = x + (size_t)growL[rA]*FIN + k0 + koffA;
  const _Float16* srcB[4];
  #pragma unroll
  for (int q = 0; q < 4; q++){
    int c2 = q*256 + t;
    int colg = ((c2 >> 6) & 7)*32 + (t & 31);
    srcB[q] = WhT + ((size_t)camc*FOUT + colg)*FIN + k0
            + (c2 >> 9)*16 + ((t >> 5) & 1)*8;
  }
  f32x16 acc[4];
  #pragma unroll
  for (int nb = 0; nb < 4; nb++)
    #pragma unroll
    for (int r = 0; r < 16; r++) acc[nb][r] = 0.f;
  int cur = 0;
  {
    f32x4 a0 = *(const f32x4*)srcA;
    f32x4 a1 = *(const f32x4*)(srcA + 4);
    #pragma unroll
    for (int q = 0; q < 4; q++) gload16(srcB[q], &ab[2048 + (q*256 + t)*8]);
    f16x8 hv;
    #pragma unroll
    for (int e = 0; e < 4; e++){ hv[e] = (_Float16)a0[e]; hv[4+e] = (_Float16)a1[e]; }
    *(f16x8*)&ab[t*8] = hv;
  }
  __syncthreads();
  for (int s = 0; s < NSTEPS; s++){
    bool have = (s + 1 < NSTEPS);
    int adv = have ? (s + 1)*32 : 0;
    f32x4 na0 = *(const f32x4*)(srcA + adv);
    f32x4 na1 = *(const f32x4*)(srcA + adv + 4);
    if (have){
      #pragma unroll
      for (int q = 0; q < 4; q++)
        gload16(srcB[q] + adv, &ab[(cur ^ 1)*10240 + 2048 + (q*256 + t)*8]);
    }
    const _Float16* base = ab + cur*10240;
    f16x8 af[2]; f16x8 bfr[2][4];
    #pragma unroll
    for (int kk = 0; kk < 2; kk++){
      af[kk] = *(const f16x8*)(base + ((kk*2 + wr)*64 + lane)*8);
      #pragma unroll
      for (int nb = 0; nb < 4; nb++)
        bfr[kk][nb] = *(const f16x8*)(base + 2048 + ((kk*8 + wc*4 + nb)*64 + lane)*8);
    }
    #pragma unroll
    for (int kk = 0; kk < 2; kk++)
      #pragma unroll
      for (int nb = 0; nb < 4; nb++)
        acc[nb] = __builtin_amdgcn_mfma_f32_32x32x16_f16(af[kk], bfr[kk][nb], acc[nb], 0, 0, 0);
    if (have){
      f16x8 hv;
      #pragma unroll
      for (int e = 0; e < 4; e++){ hv[e] = (_Float16)na0[e]; hv[4+e] = (_Float16)na1[e]; }
      *(f16x8*)&ab[(cur ^ 1)*10240 + t*8] = hv;
    }
    __syncthreads();
    cur ^= 1;
  }
  int colb = wc*128;
  #pragma unroll
  for (int nb = 0; nb < 4; nb++){
    #pragma unroll
    for (int r = 0; r < 16; r++){
      int rowl = wr*32 + (r & 3) + 8*(r >> 2) + 4*(lane >> 5);
      int grow = rows[rowl];
      if (grow >= 0)
        partial[((size_t)ks*NR + grow)*FOUT + colb + nb*32 + (lane & 31)] = acc[nb][r];
    }
  }
}

// ---------------- K3: hsum + s1/s2/bm + hT transpose (128 blocks) -------------
__global__ __launch_bounds__(256) void k_hsumT(const float* __restrict__ partial,
    const float* __restrict__ a, float* __restrict__ s1, float* __restrict__ s2,
    float* __restrict__ bm, unsigned short* __restrict__ hT){
  __shared__ __align__(16) char smem[36096];
  unsigned short* sums = (unsigned short*)smem;   // [64][264]
  float* a1l = (float*)(smem + 33792);            // [256]
  float* a2l = (float*)(smem + 34816);            // [256]
  float* redv = (float*)(smem + 35840);           // [4]
  int blk = blockIdx.x, t = threadIdx.x;
  int w = t >> 6, lane = t & 63;
  int r0 = blk*64;
  a1l[t] = a[t]; a2l[t] = a[FOUT + t];
  __syncthreads();
  float bmax = -3.0e38f;
  #pragma unroll
  for (int rep = 0; rep < 16; rep++){
    int row = rep*4 + w;
    const float* pp = partial + (size_t)(r0 + row)*FOUT + lane*4;
    f32x4 s; s[0] = s[1] = s[2] = s[3] = 0.f;
    #pragma unroll
    for (int ks = 0; ks < KS; ks++)
      s += *(const f32x4*)(pp + (size_t)ks*NR*FOUT);
    u16x4 pk;
    #pragma unroll
    for (int e = 0; e < 4; e++) pk[e] = f2bf(s[e]);
    *(u16x4*)&sums[row*264 + lane*4] = pk;
    f32x4 a1v = *(const f32x4*)&a1l[lane*4];
    f32x4 a2v = *(const f32x4*)&a2l[lane*4];
    float p1 = 0.f, p2 = 0.f;
    #pragma unroll
    for (int e = 0; e < 4; e++){ p1 = fmaf(s[e], a1v[e], p1); p2 = fmaf(s[e], a2v[e], p2); }
    #pragma unroll
    for (int off2 = 32; off2 > 0; off2 >>= 1){
      p1 += __shfl_xor(p1, off2);
      p2 += __shfl_xor(p2, off2);
    }
    if (lane == 0){
      s1[r0 + row] = p1; s2[r0 + row] = p2;
      bmax = fmaxf(bmax, p2);
    }
  }
  if (lane == 0) redv[w] = bmax;
  __syncthreads();
  if (t == 0)
    bm[blk] = fmaxf(fmaxf(redv[0], redv[1]), fmaxf(redv[2], redv[3]));
  int c = t;
  #pragma unroll
  for (int q = 0; q < 8; q++){
    u16x8 v;
    #pragma unroll
    for (int e = 0; e < 8; e++) v[e] = sums[(q*8 + e)*264 + c];
    *(u16x8*)(hT + (size_t)c*NR + r0 + q*8) = v;
  }
}

// ---------------- K4: flash (R10 structure) + fused final epilogue ------------
// Last block per i-tile (atomic counter) combines the JC partials, normalizes,
// applies ELU, writes out, and resets the counter for the next graph replay.
__global__ __launch_bounds__(512, 4) void k_flash(const int* __restrict__ adj,
    const float* __restrict__ s1g, const float* __restrict__ s2g,
    const float* __restrict__ bm, const unsigned short* __restrict__ hT,
    float* __restrict__ hp, float* __restrict__ Dp,
    int* __restrict__ fcnt, float* __restrict__ outp){
  __shared__ __align__(16) unsigned short hTl[256*64];   // 32KB, swizzled
  __shared__ __align__(16) unsigned short pl[64][72];    // 9.2KB
  __shared__ float s1l[64], ml[64], Dl[64], red[8];
  __shared__ int lastFlag;
  int blk = blockIdx.x, t = threadIdx.x;
  int w = t >> 6, lane = t & 63;
  int it = blk & 127, jc = blk >> 7;
  int i0 = it*64;
  int jbase = jc * NJ;
  {
    float v = (t < 128) ? bm[t] : -3.0e38f;
    #pragma unroll
    for (int off = 32; off > 0; off >>= 1) v = fmaxf(v, __shfl_xor(v, off));
    if (lane == 0) red[w] = v;
  }
  __syncthreads();
  if (t == 0){
    float v = red[0];
    #pragma unroll
    for (int k = 1; k < 8; k++) v = fmaxf(v, red[k]);
    red[0] = v;
  }
  __syncthreads();
  float maxS2 = red[0];
  if (t < 64){
    float sv = s1g[i0 + t];
    s1l[t] = sv;
    float mm = sv + maxS2;
    ml[t] = fmaxf(mm, ALPHA*mm);
  }
  __syncthreads();
  int il = t >> 3, tj = t & 7;
  float s1i = s1l[il], mi = ml[il];
  float Dacc = 0.f;
  f32x16 acc0, acc1;
  #pragma unroll
  for (int k = 0; k < 16; k++){ acc0[k] = 0.f; acc1[k] = 0.f; }
  const unsigned short* hsrc[4];
  int ldst[4];
  #pragma unroll
  for (int q = 0; q < 4; q++){
    int g = t + 512*q;
    int row = g >> 3, part = g & 7;
    hsrc[q] = hT + (size_t)row*NR + jbase + part*8;
    ldst[q] = row*64 + ((part ^ (row & 7))*8);
  }
  const int* arow = adj + (size_t)(i0 + il)*NR + jbase + tj*8;
  i32x4 adx[2][2];
  f32x4 s2x[2][2];
  #pragma unroll
  for (int sl = 0; sl < 2; sl++){
    adx[sl][0] = __builtin_nontemporal_load((const i32x4*)(arow + sl*64));
    adx[sl][1] = __builtin_nontemporal_load((const i32x4*)(arow + sl*64) + 1);
    s2x[sl][0] = *(const f32x4*)(s2g + jbase + sl*64 + tj*8);
    s2x[sl][1] = *(const f32x4*)(s2g + jbase + sl*64 + tj*8 + 4);
  }
  u32x4 hch[4];
  #pragma unroll
  for (int q = 0; q < 4; q++) hch[q] = *(const u32x4*)hsrc[q];
  for (int jt = 0; jt < NJ; jt += 128){
    #pragma unroll
    for (int half = 0; half < 2; half++){
      int jcur = jt + half*64;
      i32x4 c0 = adx[half][0], c1 = adx[half][1];
      f32x4 t0 = s2x[half][0], t1 = s2x[half][1];
      int jn2 = (jcur + 128 < NJ) ? jcur + 128 : 0;
      adx[half][0] = __builtin_nontemporal_load((const i32x4*)(arow + jn2));
      adx[half][1] = __builtin_nontemporal_load((const i32x4*)(arow + jn2) + 1);
      s2x[half][0] = *(const f32x4*)(s2g + jbase + jn2 + tj*8);
      s2x[half][1] = *(const f32x4*)(s2g + jbase + jn2 + tj*8 + 4);
      u16x8 pu;
      float Dloc = 0.f;
      #pragma unroll
      for (int e = 0; e < 4; e++){
        float e0 = s1i + t0[e]; e0 = fmaxf(e0, ALPHA*e0);
        float p0 = (c0[e] > 0) ? __expf(e0 - mi) : 0.f;
        unsigned short b0 = f2bf(p0); pu[e] = b0; Dloc += bf2f(b0);
        float e1 = s1i + t1[e]; e1 = fmaxf(e1, ALPHA*e1);
        float p1 = (c1[e] > 0) ? __expf(e1 - mi) : 0.f;
        unsigned short b1 = f2bf(p1); pu[e + 4] = b1; Dloc += bf2f(b1);
      }
      Dacc += Dloc;
      *(u16x8*)&pl[il][tj*8] = pu;
      #pragma unroll
      for (int q = 0; q < 4; q++) *(u32x4*)&hTl[ldst[q]] = hch[q];
      __syncthreads();
      int jn1 = (jcur + 64 < NJ) ? jcur + 64 : 0;
      #pragma unroll
      for (int q = 0; q < 4; q++) hch[q] = *(const u32x4*)(hsrc[q] + jn1);
      int nrow = w*32 + (lane & 31);
      #pragma unroll
      for (int ks = 0; ks < 4; ks++){
        int p = ks*2 + (lane >> 5);
        bf16x8 B = *(const bf16x8*)&hTl[nrow*64 + ((p ^ (nrow & 7))*8)];
        int koff = ks*16 + (lane >> 5)*8;
        bf16x8 a0 = *(const bf16x8*)&pl[lane & 31][koff];
        acc0 = __builtin_amdgcn_mfma_f32_32x32x16_bf16(a0, B, acc0, 0, 0, 0);
        bf16x8 a1 = *(const bf16x8*)&pl[32 + (lane & 31)][koff];
        acc1 = __builtin_amdgcn_mfma_f32_32x32x16_bf16(a1, B, acc1, 0, 0, 0);
      }
      __syncthreads();
    }
  }
  Dacc += __shfl_xor(Dacc, 1);
  Dacc += __shfl_xor(Dacc, 2);
  Dacc += __shfl_xor(Dacc, 4);
  if (tj == 0) Dl[il] = Dacc;
  __syncthreads();
  if (t < 64) Dp[(size_t)jc*NR + i0 + t] = Dl[t];
  float* hpb = hp + (size_t)jc*NR*FOUT;
  int col = w*32 + (lane & 31);
  #pragma unroll
  for (int r = 0; r < 16; r++){
    int rowl = (r & 3) + 8*(r >> 2) + 4*(lane >> 5);
    hpb[(size_t)(i0 + rowl)*FOUT + col] = acc0[r];
    hpb[(size_t)(i0 + 32 + rowl)*FOUT + col] = acc1[r];
  }
  // ---- fused final: last block of this i-tile combines + ELU + writes out ---
  __threadfence();               // all threads: drain stores, device-visible
  __syncthreads();
  if (t == 0){
    int done = atomicAdd(&fcnt[it], 1);
    lastFlag = (done == JC - 1);
  }
  __syncthreads();
  if (lastFlag){
    __threadfence();             // invalidate L1: see other blocks' hp/Dp
    #pragma unroll
    for (int rep = 0; rep < 8; rep++){
      int u = rep*512 + t;
      int row = i0 + (u >> 6), cg4 = (u & 63)*4;
      f32x4 s; s[0] = s[1] = s[2] = s[3] = 0.f;
      float D = 0.f;
      #pragma unroll
      for (int j = 0; j < JC; j++){
        s += *(const f32x4*)(hp + ((size_t)j*NR + row)*FOUT + cg4);
        D += Dp[(size_t)j*NR + row];
      }
      float inv = (D > 0.f) ? 1.f / D : 0.f;
      f32x4 o;
      #pragma unroll
      for (int e = 0; e < 4; e++){
        float v = s[e]*inv;
        o[e] = (v > 0.f) ? v : expm1f(v);
      }
      *(f32x4*)(outp + (size_t)row*FOUT + cg4) = o;
    }
    if (t == 0) fcnt[it] = 0;    // self-reset for next graph replay
  }
}

extern "C" void kernel_launch(void* const* d_in, const int* in_sizes, int n_in,
                              void* d_out, int out_size, void* d_ws, size_t ws_size,
                              hipStream_t stream){
  (void)in_sizes; (void)n_in; (void)out_size; (void)ws_size;
  const float* x   = (const float*)d_in[0];
  const float* W   = (const float*)d_in[1];
  const float* a   = (const float*)d_in[2];
  const int*   cam = (const int*)d_in[3];
  const int*   adj = (const int*)d_in[4];
  float* out = (float*)d_out;
  char* ws = (char*)d_ws;

  size_t off = 0;
  auto alloc = [&](size_t b) -> void* {
    void* p = ws + off; off = (off + b + 255) & ~(size_t)255; return p;
  };
  int* tileCam  = (int*)alloc((size_t)NTMAX*4);
  int* prows    = (int*)alloc((size_t)NTMAX*64*4);
  int* fcnt     = (int*)alloc(128*4);
  _Float16* WhT = (_Float16*)alloc((size_t)8*FIN*FOUT*2);
  unsigned short* hT = (unsigned short*)alloc((size_t)NR*FOUT*2);
  float* s1 = (float*)alloc((size_t)NR*4);
  float* s2 = (float*)alloc((size_t)NR*4);
  float* bm = (float*)alloc(128*4);
  float* Dp = (float*)alloc((size_t)JC*NR*4);
  float* partial = (float*)alloc((size_t)KS*NR*FOUT*4);  // KS==JC -> same size
  float* hp = partial;   // alias: partial dead after k_hsumT

  hipLaunchKernelGGL(k_pre, dim3(1025), dim3(256), 0, stream,
                     W, WhT, cam, prows, tileCam, fcnt);
  hipLaunchKernelGGL(k_gmm, dim3(NTMAX*4), dim3(256), 0, stream,
                     x, WhT, tileCam, prows, partial);
  hipLaunchKernelGGL(k_hsumT, dim3(128), dim3(256), 0, stream,
                     partial, a, s1, s2, bm, hT);
  hipLaunchKernelGGL(k_flash, dim3(512), dim3(512), 0, stream,
                     adj, s1, s2, bm, hT, hp, Dp, fcnt, out);
}

// Round 16
// 192.522 us; speedup vs baseline: 2.1074x; 2.1074x over previous
//
#include <hip/hip_runtime.h>

#define NR 8192
#define FIN 2048
#define FOUT 256
#define ALPHA 0.2f
#define NTMAX 136
#define KS 4
#define KLEN 512
#define NSTEPS 16
#define JC 4
#define NJ 2048

typedef float f32x4 __attribute__((ext_vector_type(4)));
typedef float f32x16 __attribute__((ext_vector_type(16)));
typedef int i32x4 __attribute__((ext_vector_type(4)));
typedef unsigned int u32x4 __attribute__((ext_vector_type(4)));
typedef unsigned short u16x4 __attribute__((ext_vector_type(4)));
typedef unsigned short u16x8 __attribute__((ext_vector_type(8)));
typedef __bf16 bf16x8 __attribute__((ext_vector_type(8)));
typedef _Float16 f16x8 __attribute__((ext_vector_type(8)));

__device__ __forceinline__ unsigned short f2bf(float f){
  unsigned u = __float_as_uint(f);
  return (unsigned short)((u + 0x7fffu + ((u >> 16) & 1u)) >> 16);
}
__device__ __forceinline__ float bf2f(unsigned short b){
  return __uint_as_float(((unsigned)b) << 16);
}
__device__ __forceinline__ void gload16(const void* gptr, void* lptr){
  __builtin_amdgcn_global_load_lds(
      (const __attribute__((address_space(1))) unsigned int*)gptr,
      (__attribute__((address_space(3))) unsigned int*)lptr, 16, 0, 0);
}

// ---------------- K1: fused wth (blocks 0..1023) + bucket (block 1024) --------
// Independent outputs; the serial bucket hides under the 1024 wth blocks.
// No fences/atomics/sync changes anywhere (R15 lesson: device fences are
// catastrophic across the 8 non-coherent XCD L2s).
__global__ __launch_bounds__(256) void k_pre(const float* __restrict__ W,
    _Float16* __restrict__ WhT, const int* __restrict__ cam,
    int* __restrict__ prows, int* __restrict__ tileCam){
  __shared__ __align__(16) char smem[9216];
  int blk = blockIdx.x, t = threadIdx.x;
  if (blk < 1024){
    _Float16 (*tl)[72] = (_Float16(*)[72])smem;
    int k0 = (blk & 31) << 6;
    int n0 = ((blk >> 5) & 3) << 6;
    int c = blk >> 7;
    {
      int kk = t >> 2, nq = (t & 3)*16;
      const float* src = W + ((size_t)c*FIN + k0 + kk)*FOUT + n0 + nq;
      #pragma unroll
      for (int q = 0; q < 4; q++){
        f32x4 v = *(const f32x4*)(src + q*4);
        #pragma unroll
        for (int e = 0; e < 4; e++) tl[nq + q*4 + e][kk] = (_Float16)v[e];
      }
    }
    __syncthreads();
    {
      int nn = t >> 2, kq = (t & 3)*16;
      union { u32x4 v[2]; _Float16 s[16]; } buf;
      #pragma unroll
      for (int e = 0; e < 16; e++) buf.s[e] = tl[nn][kq + e];
      u32x4* dst = (u32x4*)(WhT + ((size_t)c*FOUT + n0 + nn)*FIN + k0 + kq);
      dst[0] = buf.v[0]; dst[1] = buf.v[1];
    }
  } else {
    int (*cnt)[8] = (int(*)[8])smem;          // [256][8]
    int* scnt = (int*)(smem + 8192);          // [8]
    int* tst  = (int*)(smem + 8224);          // [9]
    int loc[8];
    #pragma unroll
    for (int c = 0; c < 8; c++) loc[c] = 0;
    for (int k = 0; k < 32; k++) loc[cam[t*32 + k] & 7]++;
    #pragma unroll
    for (int c = 0; c < 8; c++) cnt[t][c] = loc[c];
    __syncthreads();
    if (t < 8){
      int s = 0;
      for (int i = 0; i < 256; i++){ int v = cnt[i][t]; cnt[i][t] = s; s += v; }
      scnt[t] = s;
    }
    __syncthreads();
    if (t == 0){
      int ts = 0;
      for (int c = 0; c < 8; c++){ tst[c] = ts; ts += (scnt[c] + 63) >> 6; }
      tst[8] = ts;
    }
    __syncthreads();
    for (int s = t; s < NTMAX*64; s += 256) prows[s] = -1;
    if (t < NTMAX){
      int tc = -1, te = tst[8];
      if (t < te){
        #pragma unroll
        for (int c = 0; c < 8; c++)
          if (t >= tst[c] && t < tst[c+1]) tc = c;
      }
      tileCam[t] = tc;
    }
    __syncthreads();
    int off[8];
    #pragma unroll
    for (int c = 0; c < 8; c++) off[c] = cnt[t][c];
    for (int k = 0; k < 32; k++){
      int n = t*32 + k; int c = cam[n] & 7;
      int slot = off[c]++;
      prows[(tst[c] + (slot >> 6))*64 + (slot & 63)] = n;
    }
  }
}

// ---------------- K2: MFMA gather GEMM  partial[ks] = x[rows] @ W[c] ----------
__global__ __launch_bounds__(256, 3) void k_gmm(const float* __restrict__ x,
    const _Float16* __restrict__ WhT, const int* __restrict__ tileCam,
    const int* __restrict__ prows, float* __restrict__ partial){
  __shared__ __align__(16) char smem[41728];
  int item = blockIdx.x;
  int tile = item >> 2, ks = item & 3;
  int camc = tileCam[tile];
  if (camc < 0) return;
  _Float16* ab = (_Float16*)smem;            // [2][10240]
  int* rows  = (int*)(smem + 40960);         // [64]
  int* growL = (int*)(smem + 41216);         // [64]
  int t = threadIdx.x;
  if (t < 64){
    int r = prows[tile*64 + t];
    rows[t] = r; growL[t] = (r < 0) ? 0 : r;
  }
  __syncthreads();
  int lane = t & 63, w = t >> 6;
  int k0 = ks * KLEN;
  int wr = w >> 1, wc = w & 1;
  int rA = ((t >> 6) & 1)*32 + (t & 31);
  int koffA = (t >> 7)*16 + ((t >> 5) & 1)*8;
  const float* srcA = x + (size_t)growL[rA]*FIN + k0 + koffA;
  const _Float16* srcB[4];
  #pragma unroll
  for (int q = 0; q < 4; q++){
    int c2 = q*256 + t;
    int colg = ((c2 >> 6) & 7)*32 + (t & 31);
    srcB[q] = WhT + ((size_t)camc*FOUT + colg)*FIN + k0
            + (c2 >> 9)*16 + ((t >> 5) & 1)*8;
  }
  f32x16 acc[4];
  #pragma unroll
  for (int nb = 0; nb < 4; nb++)
    #pragma unroll
    for (int r = 0; r < 16; r++) acc[nb][r] = 0.f;
  int cur = 0;
  {
    f32x4 a0 = *(const f32x4*)srcA;
    f32x4 a1 = *(const f32x4*)(srcA + 4);
    #pragma unroll
    for (int q = 0; q < 4; q++) gload16(srcB[q], &ab[2048 + (q*256 + t)*8]);
    f16x8 hv;
    #pragma unroll
    for (int e = 0; e < 4; e++){ hv[e] = (_Float16)a0[e]; hv[4+e] = (_Float16)a1[e]; }
    *(f16x8*)&ab[t*8] = hv;
  }
  __syncthreads();
  for (int s = 0; s < NSTEPS; s++){
    bool have = (s + 1 < NSTEPS);
    int adv = have ? (s + 1)*32 : 0;
    f32x4 na0 = *(const f32x4*)(srcA + adv);
    f32x4 na1 = *(const f32x4*)(srcA + adv + 4);
    if (have){
      #pragma unroll
      for (int q = 0; q < 4; q++)
        gload16(srcB[q] + adv, &ab[(cur ^ 1)*10240 + 2048 + (q*256 + t)*8]);
    }
    const _Float16* base = ab + cur*10240;
    f16x8 af[2]; f16x8 bfr[2][4];
    #pragma unroll
    for (int kk = 0; kk < 2; kk++){
      af[kk] = *(const f16x8*)(base + ((kk*2 + wr)*64 + lane)*8);
      #pragma unroll
      for (int nb = 0; nb < 4; nb++)
        bfr[kk][nb] = *(const f16x8*)(base + 2048 + ((kk*8 + wc*4 + nb)*64 + lane)*8);
    }
    #pragma unroll
    for (int kk = 0; kk < 2; kk++)
      #pragma unroll
      for (int nb = 0; nb < 4; nb++)
        acc[nb] = __builtin_amdgcn_mfma_f32_32x32x16_f16(af[kk], bfr[kk][nb], acc[nb], 0, 0, 0);
    if (have){
      f16x8 hv;
      #pragma unroll
      for (int e = 0; e < 4; e++){ hv[e] = (_Float16)na0[e]; hv[4+e] = (_Float16)na1[e]; }
      *(f16x8*)&ab[(cur ^ 1)*10240 + t*8] = hv;
    }
    __syncthreads();
    cur ^= 1;
  }
  int colb = wc*128;
  #pragma unroll
  for (int nb = 0; nb < 4; nb++){
    #pragma unroll
    for (int r = 0; r < 16; r++){
      int rowl = wr*32 + (r & 3) + 8*(r >> 2) + 4*(lane >> 5);
      int grow = rows[rowl];
      if (grow >= 0)
        partial[((size_t)ks*NR + grow)*FOUT + colb + nb*32 + (lane & 31)] = acc[nb][r];
    }
  }
}

// ---------------- K3: hsum + s1/s2/bm + hT transpose (128 blocks) -------------
__global__ __launch_bounds__(256) void k_hsumT(const float* __restrict__ partial,
    const float* __restrict__ a, float* __restrict__ s1, float* __restrict__ s2,
    float* __restrict__ bm, unsigned short* __restrict__ hT){
  __shared__ __align__(16) char smem[36096];
  unsigned short* sums = (unsigned short*)smem;   // [64][264]
  float* a1l = (float*)(smem + 33792);            // [256]
  float* a2l = (float*)(smem + 34816);            // [256]
  float* redv = (float*)(smem + 35840);           // [4]
  int blk = blockIdx.x, t = threadIdx.x;
  int w = t >> 6, lane = t & 63;
  int r0 = blk*64;
  a1l[t] = a[t]; a2l[t] = a[FOUT + t];
  __syncthreads();
  float bmax = -3.0e38f;
  #pragma unroll
  for (int rep = 0; rep < 16; rep++){
    int row = rep*4 + w;
    const float* pp = partial + (size_t)(r0 + row)*FOUT + lane*4;
    f32x4 s; s[0] = s[1] = s[2] = s[3] = 0.f;
    #pragma unroll
    for (int ks = 0; ks < KS; ks++)
      s += *(const f32x4*)(pp + (size_t)ks*NR*FOUT);
    u16x4 pk;
    #pragma unroll
    for (int e = 0; e < 4; e++) pk[e] = f2bf(s[e]);
    *(u16x4*)&sums[row*264 + lane*4] = pk;
    f32x4 a1v = *(const f32x4*)&a1l[lane*4];
    f32x4 a2v = *(const f32x4*)&a2l[lane*4];
    float p1 = 0.f, p2 = 0.f;
    #pragma unroll
    for (int e = 0; e < 4; e++){ p1 = fmaf(s[e], a1v[e], p1); p2 = fmaf(s[e], a2v[e], p2); }
    #pragma unroll
    for (int off2 = 32; off2 > 0; off2 >>= 1){
      p1 += __shfl_xor(p1, off2);
      p2 += __shfl_xor(p2, off2);
    }
    if (lane == 0){
      s1[r0 + row] = p1; s2[r0 + row] = p2;
      bmax = fmaxf(bmax, p2);
    }
  }
  if (lane == 0) redv[w] = bmax;
  __syncthreads();
  if (t == 0)
    bm[blk] = fmaxf(fmaxf(redv[0], redv[1]), fmaxf(redv[2], redv[3]));
  int c = t;
  #pragma unroll
  for (int q = 0; q < 8; q++){
    u16x8 v;
    #pragma unroll
    for (int e = 0; e < 8; e++) v[e] = sums[(q*8 + e)*264 + c];
    *(u16x8*)(hT + (size_t)c*NR + r0 + q*8) = v;
  }
}

// ---------------- K4: flash attention, LDS-staged hT, depth-2 adj/s2 prefetch -
__global__ __launch_bounds__(512, 4) void k_flash(const int* __restrict__ adj,
    const float* __restrict__ s1g, const float* __restrict__ s2g,
    const float* __restrict__ bm, const unsigned short* __restrict__ hT,
    float* __restrict__ hp, float* __restrict__ Dp){
  __shared__ __align__(16) unsigned short hTl[256*64];   // 32KB, swizzled
  __shared__ __align__(16) unsigned short pl[64][72];    // 9.2KB
  __shared__ float s1l[64], ml[64], Dl[64], red[8];
  int blk = blockIdx.x, t = threadIdx.x;
  int w = t >> 6, lane = t & 63;
  int it = blk & 127, jc = blk >> 7;
  int i0 = it*64;
  int jbase = jc * NJ;
  {
    float v = (t < 128) ? bm[t] : -3.0e38f;
    #pragma unroll
    for (int off = 32; off > 0; off >>= 1) v = fmaxf(v, __shfl_xor(v, off));
    if (lane == 0) red[w] = v;
  }
  __syncthreads();
  if (t == 0){
    float v = red[0];
    #pragma unroll
    for (int k = 1; k < 8; k++) v = fmaxf(v, red[k]);
    red[0] = v;
  }
  __syncthreads();
  float maxS2 = red[0];
  if (t < 64){
    float sv = s1g[i0 + t];
    s1l[t] = sv;
    float mm = sv + maxS2;
    ml[t] = fmaxf(mm, ALPHA*mm);
  }
  __syncthreads();
  int il = t >> 3, tj = t & 7;
  float s1i = s1l[il], mi = ml[il];
  float Dacc = 0.f;
  f32x16 acc0, acc1;
  #pragma unroll
  for (int k = 0; k < 16; k++){ acc0[k] = 0.f; acc1[k] = 0.f; }
  const unsigned short* hsrc[4];
  int ldst[4];
  #pragma unroll
  for (int q = 0; q < 4; q++){
    int g = t + 512*q;
    int row = g >> 3, part = g & 7;
    hsrc[q] = hT + (size_t)row*NR + jbase + part*8;
    ldst[q] = row*64 + ((part ^ (row & 7))*8);
  }
  const int* arow = adj + (size_t)(i0 + il)*NR + jbase + tj*8;
  i32x4 adx[2][2];
  f32x4 s2x[2][2];
  #pragma unroll
  for (int sl = 0; sl < 2; sl++){
    adx[sl][0] = __builtin_nontemporal_load((const i32x4*)(arow + sl*64));
    adx[sl][1] = __builtin_nontemporal_load((const i32x4*)(arow + sl*64) + 1);
    s2x[sl][0] = *(const f32x4*)(s2g + jbase + sl*64 + tj*8);
    s2x[sl][1] = *(const f32x4*)(s2g + jbase + sl*64 + tj*8 + 4);
  }
  u32x4 hch[4];
  #pragma unroll
  for (int q = 0; q < 4; q++) hch[q] = *(const u32x4*)hsrc[q];
  for (int jt = 0; jt < NJ; jt += 128){
    #pragma unroll
    for (int half = 0; half < 2; half++){
      int jcur = jt + half*64;
      i32x4 c0 = adx[half][0], c1 = adx[half][1];
      f32x4 t0 = s2x[half][0], t1 = s2x[half][1];
      int jn2 = (jcur + 128 < NJ) ? jcur + 128 : 0;
      adx[half][0] = __builtin_nontemporal_load((const i32x4*)(arow + jn2));
      adx[half][1] = __builtin_nontemporal_load((const i32x4*)(arow + jn2) + 1);
      s2x[half][0] = *(const f32x4*)(s2g + jbase + jn2 + tj*8);
      s2x[half][1] = *(const f32x4*)(s2g + jbase + jn2 + tj*8 + 4);
      u16x8 pu;
      float Dloc = 0.f;
      #pragma unroll
      for (int e = 0; e < 4; e++){
        float e0 = s1i + t0[e]; e0 = fmaxf(e0, ALPHA*e0);
        float p0 = (c0[e] > 0) ? __expf(e0 - mi) : 0.f;
        unsigned short b0 = f2bf(p0); pu[e] = b0; Dloc += bf2f(b0);
        float e1 = s1i + t1[e]; e1 = fmaxf(e1, ALPHA*e1);
        float p1 = (c1[e] > 0) ? __expf(e1 - mi) : 0.f;
        unsigned short b1 = f2bf(p1); pu[e + 4] = b1; Dloc += bf2f(b1);
      }
      Dacc += Dloc;
      *(u16x8*)&pl[il][tj*8] = pu;
      #pragma unroll
      for (int q = 0; q < 4; q++) *(u32x4*)&hTl[ldst[q]] = hch[q];
      __syncthreads();
      int jn1 = (jcur + 64 < NJ) ? jcur + 64 : 0;
      #pragma unroll
      for (int q = 0; q < 4; q++) hch[q] = *(const u32x4*)(hsrc[q] + jn1);
      int nrow = w*32 + (lane & 31);
      #pragma unroll
      for (int ks = 0; ks < 4; ks++){
        int p = ks*2 + (lane >> 5);
        bf16x8 B = *(const bf16x8*)&hTl[nrow*64 + ((p ^ (nrow & 7))*8)];
        int koff = ks*16 + (lane >> 5)*8;
        bf16x8 a0 = *(const bf16x8*)&pl[lane & 31][koff];
        acc0 = __builtin_amdgcn_mfma_f32_32x32x16_bf16(a0, B, acc0, 0, 0, 0);
        bf16x8 a1 = *(const bf16x8*)&pl[32 + (lane & 31)][koff];
        acc1 = __builtin_amdgcn_mfma_f32_32x32x16_bf16(a1, B, acc1, 0, 0, 0);
      }
      __syncthreads();
    }
  }
  Dacc += __shfl_xor(Dacc, 1);
  Dacc += __shfl_xor(Dacc, 2);
  Dacc += __shfl_xor(Dacc, 4);
  if (tj == 0) Dl[il] = Dacc;
  __syncthreads();
  if (t < 64) Dp[(size_t)jc*NR + i0 + t] = Dl[t];
  float* hpb = hp + (size_t)jc*NR*FOUT;
  int col = w*32 + (lane & 31);
  #pragma unroll
  for (int r = 0; r < 16; r++){
    int rowl = (r & 3) + 8*(r >> 2) + 4*(lane >> 5);
    hpb[(size_t)(i0 + rowl)*FOUT + col] = acc0[r];
    hpb[(size_t)(i0 + 32 + rowl)*FOUT + col] = acc1[r];
  }
}

// ---------------- K5: combine partials, normalize, ELU ------------------------
__global__ __launch_bounds__(256) void k_final(const float* __restrict__ hp,
    const float* __restrict__ Dp, float* __restrict__ out){
  int g = blockIdx.x*256 + threadIdx.x;
  int i = g >> 6, cg4 = (g & 63)*4;
  f32x4 s; s[0] = s[1] = s[2] = s[3] = 0.f;
  float D = 0.f;
  #pragma unroll
  for (int jc = 0; jc < JC; jc++){
    s += *(const f32x4*)(hp + ((size_t)jc*NR + i)*FOUT + cg4);
    D += Dp[(size_t)jc*NR + i];
  }
  float inv = (D > 0.f) ? 1.f / D : 0.f;
  f32x4 o;
  #pragma unroll
  for (int e = 0; e < 4; e++){
    float v = s[e]*inv;
    o[e] = (v > 0.f) ? v : expm1f(v);
  }
  *(f32x4*)(out + (size_t)i*FOUT + cg4) = o;
}

extern "C" void kernel_launch(void* const* d_in, const int* in_sizes, int n_in,
                              void* d_out, int out_size, void* d_ws, size_t ws_size,
                              hipStream_t stream){
  (void)in_sizes; (void)n_in; (void)out_size; (void)ws_size;
  const float* x   = (const float*)d_in[0];
  const float* W   = (const float*)d_in[1];
  const float* a   = (const float*)d_in[2];
  const int*   cam = (const int*)d_in[3];
  const int*   adj = (const int*)d_in[4];
  float* out = (float*)d_out;
  char* ws = (char*)d_ws;

  size_t off = 0;
  auto alloc = [&](size_t b) -> void* {
    void* p = ws + off; off = (off + b + 255) & ~(size_t)255; return p;
  };
  int* tileCam  = (int*)alloc((size_t)NTMAX*4);
  int* prows    = (int*)alloc((size_t)NTMAX*64*4);
  _Float16* WhT = (_Float16*)alloc((size_t)8*FIN*FOUT*2);
  unsigned short* hT = (unsigned short*)alloc((size_t)NR*FOUT*2);
  float* s1 = (float*)alloc((size_t)NR*4);
  float* s2 = (float*)alloc((size_t)NR*4);
  float* bm = (float*)alloc(128*4);
  float* Dp = (float*)alloc((size_t)JC*NR*4);
  float* partial = (float*)alloc((size_t)KS*NR*FOUT*4);  // KS==JC -> same size
  float* hp = partial;   // alias: partial dead after k_hsumT

  hipLaunchKernelGGL(k_pre, dim3(1025), dim3(256), 0, stream,
                     W, WhT, cam, prows, tileCam);
  hipLaunchKernelGGL(k_gmm, dim3(NTMAX*4), dim3(256), 0, stream,
                     x, WhT, tileCam, prows, partial);
  hipLaunchKernelGGL(k_hsumT, dim3(128), dim3(256), 0, stream,
                     partial, a, s1, s2, bm, hT);
  hipLaunchKernelGGL(k_flash, dim3(512), dim3(512), 0, stream,
                     adj, s1, s2, bm, hT, hp, Dp);
  hipLaunchKernelGGL(k_final, dim3((NR*FOUT/4)/256), dim3(256), 0, stream,
                     hp, Dp, out);
}